// Round 5
// baseline (712.368 us; speedup 1.0000x reference)
//
#include <hip/hip_runtime.h>
#include <math.h>

#define Bc 16
#define Lc 2048
#define BLc (Bc*Lc)
#define NSUB 16
#define HN 262144   // 16*512*32 state lanes

typedef __attribute__((ext_vector_type(8))) short bf16x8;
typedef __attribute__((ext_vector_type(4))) float f32x4;

__device__ __forceinline__ float softplusf(float v) {
    return (v > 20.f) ? v : log1pf(__expf(v));
}
__device__ __forceinline__ float siluf(float v) {
    return v / (1.f + __expf(-v));
}
__device__ __forceinline__ unsigned short f2b(float f) {   // RNE f32->bf16
    union { float f; unsigned u; } v; v.f = f;
    unsigned r = v.u + 0x7FFFu + ((v.u >> 16) & 1u);
    return (unsigned short)(r >> 16);
}
__device__ __forceinline__ float b2f(unsigned short b) {
    union { unsigned u; float f; } v; v.u = ((unsigned)b) << 16;
    return v.f;
}

__global__ __launch_bounds__(256) void zero_kernel(float* p, int n) {
    int i = blockIdx.x * 256 + threadIdx.x;
    if (i < n) p[i] = 0.f;
}

__global__ __launch_bounds__(256) void cvt_bf16(const float* __restrict__ s,
                                                unsigned short* __restrict__ d, int n) {
    int i = blockIdx.x * 256 + threadIdx.x;
    if (i < n) d[i] = f2b(s[i]);
}

// ---------------- bf16 MFMA GEMM (NT): C[m,n] = act(bias[n] + sum_k A[arow(m)][k]*W[n][k])
__global__ __launch_bounds__(256) void gemm_mfma(
    const unsigned short* __restrict__ A, int K, int aRS, int al0,
    const unsigned short* __restrict__ W,
    float* __restrict__ outF, unsigned short* __restrict__ outB,
    const float* __restrict__ bias, int act,
    int oRS, int ol0, int logCL, int N)
{
    const int lane = threadIdx.x & 63;
    const int w = threadIdx.x >> 6;
    const int wr = w >> 1, wc = w & 1;
    const int m_base = blockIdx.y * 128 + wr * 64;
    const int n_base = blockIdx.x * 128 + wc * 64;
    if (n_base >= N) return;
    const int r = lane & 15, q = lane >> 4;
    const int clm = (1 << logCL) - 1;

    int ntiles = (N - n_base + 15) >> 4; if (ntiles > 4) ntiles = 4;

    const unsigned short* aptr[4];
    #pragma unroll
    for (int mi = 0; mi < 4; ++mi) {
        int m = m_base + mi * 16 + r;
        int arow = ((m >> logCL) * aRS) + al0 + (m & clm);
        aptr[mi] = A + (size_t)arow * K + q * 8;
    }
    const unsigned short* bptr[4];
    #pragma unroll
    for (int ni = 0; ni < 4; ++ni) {
        int nt = n_base + ni * 16;
        bptr[ni] = W + (size_t)((nt < N) ? (nt + r) : 0) * K + q * 8;
    }

    f32x4 acc[4][4];
    #pragma unroll
    for (int mi = 0; mi < 4; ++mi)
        #pragma unroll
        for (int ni = 0; ni < 4; ++ni)
            acc[mi][ni] = (f32x4){0.f, 0.f, 0.f, 0.f};

    for (int k0 = 0; k0 < K; k0 += 32) {
        bf16x8 a[4], b[4];
        #pragma unroll
        for (int mi = 0; mi < 4; ++mi) a[mi] = *(const bf16x8*)(aptr[mi] + k0);
        #pragma unroll
        for (int ni = 0; ni < 4; ++ni) if (ni < ntiles) b[ni] = *(const bf16x8*)(bptr[ni] + k0);
        #pragma unroll
        for (int mi = 0; mi < 4; ++mi)
            #pragma unroll
            for (int ni = 0; ni < 4; ++ni)
                if (ni < ntiles)
                    acc[mi][ni] = __builtin_amdgcn_mfma_f32_16x16x32_bf16(a[mi], b[ni], acc[mi][ni], 0, 0, 0);
    }

    #pragma unroll
    for (int ni = 0; ni < 4; ++ni) {
        if (ni >= ntiles) continue;
        int n = n_base + ni * 16 + r;
        float bs = bias ? bias[n] : 0.f;
        #pragma unroll
        for (int mi = 0; mi < 4; ++mi) {
            #pragma unroll
            for (int rr = 0; rr < 4; ++rr) {
                int m = m_base + mi * 16 + q * 4 + rr;
                float v = acc[mi][ni][rr] + bs;
                if (act == 1) v = (v > 0.f) ? v : 0.01f * v;
                else if (act == 2) v = 1.f / (1.f + __expf(-v));
                size_t orow = ((size_t)(m >> logCL)) * oRS + ol0 + (m & clm);
                if (outF) outF[orow * N + n] = v;
                else      outB[orow * N + n] = f2b(v);
            }
        }
    }
}

// ---------------- fp32 tiled GEMM (kept for the K=16 dt projection)
__global__ __launch_bounds__(256) void gemm_nt(
    const float* __restrict__ A, int lda, int bRS, int l0, int logCL,
    const float* __restrict__ W,
    float* __restrict__ C,
    const float* __restrict__ bias, int act,
    int N, int K)
{
    __shared__ float As[16][68];
    __shared__ float Ws[16][68];
    const int m0 = blockIdx.y * 64;
    const int n0 = blockIdx.x * 64;
    const int tid = threadIdx.x;
    const int tx = tid & 15, ty = tid >> 4;
    const int clm = (1 << logCL) - 1;

    float acc[4][4] = {};

    for (int k0 = 0; k0 < K; k0 += 16) {
        #pragma unroll
        for (int rr = 0; rr < 4; ++rr) {
            int lin = tid + rr * 256;
            int k = lin & 15, mm = lin >> 4;
            int m = m0 + mm;
            int arow = ((m >> logCL) * bRS) + l0 + (m & clm);
            As[k][mm] = A[(size_t)arow * lda + k0 + k];
            int n = n0 + mm;
            Ws[k][mm] = (n < N) ? W[(size_t)n * K + k0 + k] : 0.f;
        }
        __syncthreads();
        #pragma unroll
        for (int kk = 0; kk < 16; ++kk) {
            float4 av = *(const float4*)&As[kk][ty * 4];
            float4 bv = *(const float4*)&Ws[kk][tx * 4];
            float a_[4] = {av.x, av.y, av.z, av.w};
            float b_[4] = {bv.x, bv.y, bv.z, bv.w};
            #pragma unroll
            for (int i = 0; i < 4; ++i)
                #pragma unroll
                for (int j = 0; j < 4; ++j)
                    acc[i][j] += a_[i] * b_[j];
        }
        __syncthreads();
    }

    #pragma unroll
    for (int i = 0; i < 4; ++i) {
        int m = m0 + ty * 4 + i;
        #pragma unroll
        for (int j = 0; j < 4; ++j) {
            int n = n0 + tx * 4 + j;
            if (n < N) {
                float v = acc[i][j];
                if (bias) v += bias[n];
                if (act == 1) v = softplusf(v);
                C[(size_t)m * N + n] = v;
            }
        }
    }
}

// depthwise causal conv (width 4) + SiLU -> u (bf16), chunk-local with halo carry
__global__ __launch_bounds__(256) void conv_silu(
    const float* __restrict__ xcC, const float* __restrict__ carry,
    const float* __restrict__ cw, const float* __restrict__ cb,
    unsigned short* __restrict__ uB, int logCL)
{
    int idx = blockIdx.x * 256 + threadIdx.x;
    int e = idx & 511;
    int row = idx >> 9;
    int ll = row & ((1 << logCL) - 1);
    int b = row >> logCL;
    float acc = cb[e];
    #pragma unroll
    for (int k = 0; k < 4; ++k) {
        int j = ll + k - 3;
        float xv;
        if (j >= 0) xv = xcC[(size_t)(row + k - 3) * 512 + e];
        else        xv = carry[(size_t)(b * 3 + (j + 3)) * 512 + e];
        acc += xv * cw[e * 4 + k];
    }
    uB[idx] = f2b(siluf(acc));
}

__global__ __launch_bounds__(256) void carry_save(
    const float* __restrict__ xcC, float* __restrict__ carry, int CL)
{
    int idx = blockIdx.x * 256 + threadIdx.x;
    int e = idx & 511;
    int t = idx >> 9;
    int b = t / 3, i = t - 3 * b;
    carry[idx] = xcC[(size_t)(b * CL + CL - 3 + i) * 512 + e];
}

// ---- scan pass 1: 8 states/lane, 4 lanes per d. lane = sg*16 + dlo.
// grid: Bc * 8 * NSUB blocks; block covers 64 d (16 per wave).
__global__ __launch_bounds__(256) void scan_pass1(
    const float* __restrict__ dtC, const unsigned short* __restrict__ uB,
    const float* __restrict__ dbcC, const float* __restrict__ A_log,
    float* __restrict__ aprodB, float* __restrict__ hendB,
    int CL, int Lch)
{
    const int lane = threadIdx.x & 63;
    const int w = threadIdx.x >> 6;
    const int dlo = lane & 15, sg = lane >> 4;        // sg: 0..3
    const int bi = blockIdx.x;
    const int c    = bi & (NSUB - 1);
    const int dblk = (bi >> 4) & 7;
    const int b    = bi >> 7;
    const int d    = dblk * 64 + w * 16 + dlo;
    const int s0   = sg * 8;

    float acoef[8];
    #pragma unroll
    for (int g = 0; g < 2; ++g) {
        float4 al = *(const float4*)&A_log[d * 32 + s0 + 4 * g];
        acoef[4*g+0] = -__expf(al.x);
        acoef[4*g+1] = -__expf(al.y);
        acoef[4*g+2] = -__expf(al.z);
        acoef[4*g+3] = -__expf(al.w);
    }

    float h[8];
    #pragma unroll
    for (int s = 0; s < 8; ++s) h[s] = 0.f;
    float dtsum = 0.f;

    size_t row = (size_t)b * CL + (size_t)c * Lch;
    size_t off = row * 512 + d;
    size_t r80 = row * 80 + 16 + s0;
    for (int j = 0; j < Lch; ++j) {
        float dtv = dtC[off];
        float uv  = b2f(uB[off]);
        float dtu = dtv * uv;
        dtsum += dtv;
        float4 B0 = *(const float4*)&dbcC[r80];
        float4 B1 = *(const float4*)&dbcC[r80 + 4];
        h[0] = __expf(dtv * acoef[0]) * h[0] + dtu * B0.x;
        h[1] = __expf(dtv * acoef[1]) * h[1] + dtu * B0.y;
        h[2] = __expf(dtv * acoef[2]) * h[2] + dtu * B0.z;
        h[3] = __expf(dtv * acoef[3]) * h[3] + dtu * B0.w;
        h[4] = __expf(dtv * acoef[4]) * h[4] + dtu * B1.x;
        h[5] = __expf(dtv * acoef[5]) * h[5] + dtu * B1.y;
        h[6] = __expf(dtv * acoef[6]) * h[6] + dtu * B1.z;
        h[7] = __expf(dtv * acoef[7]) * h[7] + dtu * B1.w;
        off += 512; r80 += 80;
    }

    size_t o = (size_t)c * HN + ((size_t)(b * 512 + d)) * 32 + s0;
    *(float4*)&hendB[o]     = make_float4(h[0], h[1], h[2], h[3]);
    *(float4*)&hendB[o + 4] = make_float4(h[4], h[5], h[6], h[7]);
    *(float4*)&aprodB[o]     = make_float4(__expf(acoef[0]*dtsum), __expf(acoef[1]*dtsum),
                                           __expf(acoef[2]*dtsum), __expf(acoef[3]*dtsum));
    *(float4*)&aprodB[o + 4] = make_float4(__expf(acoef[4]*dtsum), __expf(acoef[5]*dtsum),
                                           __expf(acoef[6]*dtsum), __expf(acoef[7]*dtsum));
}

// ---- fixup: chain subchunk states per (b,d,s); hinit overwrites aprod slot in place
__global__ __launch_bounds__(256) void scan_fixup(
    float* __restrict__ aprodB, const float* __restrict__ hendB,
    float* __restrict__ hbuf)
{
    int idx = blockIdx.x * 256 + threadIdx.x;   // [0, HN)
    float h = hbuf[idx];
    #pragma unroll
    for (int c = 0; c < NSUB; ++c) {
        size_t o = (size_t)c * HN + idx;
        float a = aprodB[o];
        float e = hendB[o];
        aprodB[o] = h;           // becomes h_init for subchunk c
        h = a * h + e;
    }
    hbuf[idx] = h;
}

// ---- scan pass 2: 8 states/lane, y via 2 shfl_xor (off h-critical-path)
__global__ __launch_bounds__(256) void scan_pass2(
    const float* __restrict__ dtC, const unsigned short* __restrict__ uB,
    const float* __restrict__ dbcC, const unsigned short* __restrict__ zB,
    const float* __restrict__ A_log, const float* __restrict__ Dv,
    const float* __restrict__ hinitB, unsigned short* __restrict__ yB,
    int CL, int Lch)
{
    const int lane = threadIdx.x & 63;
    const int w = threadIdx.x >> 6;
    const int dlo = lane & 15, sg = lane >> 4;
    const int bi = blockIdx.x;
    const int c    = bi & (NSUB - 1);
    const int dblk = (bi >> 4) & 7;
    const int b    = bi >> 7;
    const int d    = dblk * 64 + w * 16 + dlo;
    const int s0   = sg * 8;

    float acoef[8];
    #pragma unroll
    for (int g = 0; g < 2; ++g) {
        float4 al = *(const float4*)&A_log[d * 32 + s0 + 4 * g];
        acoef[4*g+0] = -__expf(al.x);
        acoef[4*g+1] = -__expf(al.y);
        acoef[4*g+2] = -__expf(al.z);
        acoef[4*g+3] = -__expf(al.w);
    }
    const float Dd = Dv[d];

    float h[8];
    size_t o = (size_t)c * HN + ((size_t)(b * 512 + d)) * 32 + s0;
    {
        float4 h0 = *(const float4*)&hinitB[o];
        float4 h1 = *(const float4*)&hinitB[o + 4];
        h[0]=h0.x; h[1]=h0.y; h[2]=h0.z; h[3]=h0.w;
        h[4]=h1.x; h[5]=h1.y; h[6]=h1.z; h[7]=h1.w;
    }

    size_t row = (size_t)b * CL + (size_t)c * Lch;
    size_t off = row * 512 + d;
    size_t r80 = row * 80 + 16 + s0;
    for (int j = 0; j < Lch; ++j) {
        float dtv = dtC[off];
        float uv  = b2f(uB[off]);
        float zv  = b2f(zB[off]);
        float dtu = dtv * uv;
        float4 B0 = *(const float4*)&dbcC[r80];
        float4 B1 = *(const float4*)&dbcC[r80 + 4];
        float4 C0 = *(const float4*)&dbcC[r80 + 32];
        float4 C1 = *(const float4*)&dbcC[r80 + 36];
        float y;
        h[0] = __expf(dtv * acoef[0]) * h[0] + dtu * B0.x;  y  = h[0] * C0.x;
        h[1] = __expf(dtv * acoef[1]) * h[1] + dtu * B0.y;  y += h[1] * C0.y;
        h[2] = __expf(dtv * acoef[2]) * h[2] + dtu * B0.z;  y += h[2] * C0.z;
        h[3] = __expf(dtv * acoef[3]) * h[3] + dtu * B0.w;  y += h[3] * C0.w;
        h[4] = __expf(dtv * acoef[4]) * h[4] + dtu * B1.x;  y += h[4] * C1.x;
        h[5] = __expf(dtv * acoef[5]) * h[5] + dtu * B1.y;  y += h[5] * C1.y;
        h[6] = __expf(dtv * acoef[6]) * h[6] + dtu * B1.z;  y += h[6] * C1.z;
        h[7] = __expf(dtv * acoef[7]) * h[7] + dtu * B1.w;  y += h[7] * C1.w;
        y += __shfl_xor(y, 16, 64);
        y += __shfl_xor(y, 32, 64);
        if (sg == 0)
            yB[off] = f2b((y + uv * Dd) * siluf(zv));
        off += 512; r80 += 80;
    }
}

extern "C" void kernel_launch(void* const* d_in, const int* in_sizes, int n_in,
                              void* d_out, int out_size, void* d_ws, size_t ws_size,
                              hipStream_t stream) {
    const float* x      = (const float*)d_in[0];
    const float* W_in   = (const float*)d_in[1];
    const float* conv_w = (const float*)d_in[2];
    const float* conv_b = (const float*)d_in[3];
    const float* W_xproj= (const float*)d_in[4];
    const float* W_dt   = (const float*)d_in[5];
    const float* b_dt   = (const float*)d_in[6];
    const float* A_log  = (const float*)d_in[7];
    const float* Dv     = (const float*)d_in[8];
    const float* W_out  = (const float*)d_in[9];
    const float* W_ff1  = (const float*)d_in[10];
    const float* b_ff1  = (const float*)d_in[11];
    const float* W_ff2  = (const float*)d_in[12];
    const float* b_ff2  = (const float*)d_in[13];
    float* out = (float*)d_out;

    const size_t FIXED = 262144ull + 24576 + 4194304ull * 3 + 225280;
    int NC = 32;
    for (int c = 1; c <= 32; c <<= 1) {
        size_t M = (size_t)BLc / c;
        size_t need = (FIXED + M * 1616ull) * 4ull;
        if (need <= ws_size) { NC = c; break; }
    }
    const int CL = Lc / NC;
    int logCL = 0; while ((1 << logCL) < CL) ++logCL;
    const int Lch = CL / NSUB;
    const size_t M = (size_t)BLc / NC;

    float* ws = (float*)d_ws;
    float* hbuf   = ws;                        // 262144
    float* carry  = hbuf + 262144;             // 24576
    float* aprodB = carry + 24576;             // NSUB*HN = 4194304 (reused as hinit)
    float* hendB  = aprodB + 4194304;          // 4194304
    unsigned short* xb   = (unsigned short*)(hendB + 4194304);  // BLc*256 shorts
    unsigned short* wInb = xb + (size_t)BLc * 256;              // 262144 sh
    unsigned short* wXb  = wInb + 262144;                       // 40960 sh
    unsigned short* wOb  = wXb + 40960;                         // 131072 sh
    unsigned short* wF1b = wOb + 131072;                        // 8192 sh
    unsigned short* wF2b = wF1b + 8192;                         // 8192 sh
    float* xcC  = (float*)(wF2b + 8192);       // M*512 f32
    unsigned short* zB = (unsigned short*)(xcC + M * 512);      // M*512 sh
    unsigned short* uB = zB + M * 512;                          // M*512 sh
    float* dtC  = (float*)(uB + M * 512);      // M*512 f32
    float* dbcC = dtC + M * 512;               // M*80 f32
    unsigned short* yB  = (unsigned short*)xcC;            // M*512 sh
    unsigned short* moB = (unsigned short*)(xcC + M * 256);// M*256 sh
    unsigned short* hB  = (unsigned short*)(xcC + M * 384);// M*32 sh

    dim3 blk(256);

    zero_kernel<<<(286720 + 255) / 256, blk, 0, stream>>>(ws, 286720);

    cvt_bf16<<<(BLc * 256 + 255) / 256, blk, 0, stream>>>(x, xb, BLc * 256);
    cvt_bf16<<<(262144 + 255) / 256, blk, 0, stream>>>(W_in, wInb, 262144);
    cvt_bf16<<<(40960 + 255) / 256, blk, 0, stream>>>(W_xproj, wXb, 40960);
    cvt_bf16<<<(131072 + 255) / 256, blk, 0, stream>>>(W_out, wOb, 131072);
    cvt_bf16<<<(8192 + 255) / 256, blk, 0, stream>>>(W_ff1, wF1b, 8192);
    cvt_bf16<<<(8192 + 255) / 256, blk, 0, stream>>>(W_ff2, wF2b, 8192);

    for (int c = 0; c < NC; ++c) {
        const int l0 = c * CL;

        gemm_mfma<<<dim3(4, M / 128), blk, 0, stream>>>(xb, 256, Lc, l0, wInb,
            xcC, nullptr, nullptr, 0, CL, 0, logCL, 512);
        gemm_mfma<<<dim3(4, M / 128), blk, 0, stream>>>(xb, 256, Lc, l0, wInb + 512 * 256,
            nullptr, zB, nullptr, 0, CL, 0, logCL, 512);

        conv_silu<<<(M * 512) / 256, blk, 0, stream>>>(xcC, carry, conv_w, conv_b, uB, logCL);
        carry_save<<<96, blk, 0, stream>>>(xcC, carry, CL);

        gemm_mfma<<<dim3(1, M / 128), blk, 0, stream>>>(uB, 512, CL, 0, wXb,
            dbcC, nullptr, nullptr, 0, CL, 0, logCL, 80);

        gemm_nt<<<dim3(8, M / 64), blk, 0, stream>>>(dbcC, 80, CL, 0, logCL, W_dt, dtC, b_dt, 1, 512, 16);

        // two-pass chunk-parallel selective scan (8 states/lane, 2048 blocks)
        scan_pass1<<<Bc * 8 * NSUB, blk, 0, stream>>>(dtC, uB, dbcC, A_log, aprodB, hendB, CL, Lch);
        scan_fixup<<<HN / 256, blk, 0, stream>>>(aprodB, hendB, hbuf);
        scan_pass2<<<Bc * 8 * NSUB, blk, 0, stream>>>(dtC, uB, dbcC, zB, A_log, Dv, aprodB, yB, CL, Lch);

        gemm_mfma<<<dim3(2, M / 128), blk, 0, stream>>>(yB, 512, CL, 0, wOb,
            nullptr, moB, nullptr, 0, CL, 0, logCL, 256);

        gemm_mfma<<<dim3(1, M / 128), blk, 0, stream>>>(moB, 256, CL, 0, wF1b,
            nullptr, hB, b_ff1, 1, CL, 0, logCL, 32);
        gemm_mfma<<<dim3(2, M / 128), blk, 0, stream>>>(hB, 32, CL, 0, wF2b,
            out, nullptr, b_ff2, 2, Lc, l0, logCL, 256);
    }
}